// Round 1
// baseline (384.083 us; speedup 1.0000x reference)
//
#include <hip/hip_runtime.h>
#include <math.h>

#define H  1024
#define B  64
#define T  1024
#define BT (B*T)       // 65536
#define TC 32          // t-columns per chunk (128 B per row = full line)
#define SPLIT 4        // blocks per b -> grid 256 = exactly 1 block/CU
#define CHUNKS 8       // (T/SPLIT)/TC
#define NT 512         // 8 waves

typedef __attribute__((address_space(1))) unsigned int* gp_t;
typedef __attribute__((address_space(3))) unsigned int* lp_t;

__device__ __forceinline__ float ex2(float x) { return __builtin_amdgcn_exp2f(x); }

// Raw barriers: lgkm-only waits so the async global->LDS prefetch (vmcnt)
// STAYS IN FLIGHT across the P1/P2 reduction barriers. __syncthreads()
// would emit s_waitcnt vmcnt(0) and serialize the pipeline (the known
// barrier-drain problem). vmcnt(0) only at the chunk boundary (BAR_ALL).
#define BAR_LGKM() do { asm volatile("s_waitcnt lgkmcnt(0)" ::: "memory"); \
                        __builtin_amdgcn_s_barrier(); } while (0)
#define BAR_ALL()  do { asm volatile("s_waitcnt vmcnt(0) lgkmcnt(0)" ::: "memory"); \
                        __builtin_amdgcn_s_barrier(); } while (0)

// One block = (b, split), 1 block/CU (LDS-bound: 131 KB). Per chunk:
// 1024 rows x 32 t staged in LDS by global_load_lds (zero VGPR cost),
// then moved to registers (thread owns 16 rows x 4 t = 64 floats) while
// the NEXT chunk's DMA streams underneath P1-P3. Register live set ~115;
// no waves_per_eu cap needed (2 waves/SIMD -> 256-VGPR budget, no spill).
__global__ __launch_bounds__(NT)
void attn_main(const float* __restrict__ dec,
               const float* __restrict__ enc,
               float* __restrict__ ws)
{
    __shared__ float buf[H * TC];      // 128 KB staging, row-major [h][tc]
    __shared__ float rbuf[3][8][TC];   // [qty][wave][t]  3 KB
    __shared__ float prm[2][TC];       // per-t params

    const int tid   = threadIdx.x;
    const int split = blockIdx.x;
    const int b     = blockIdx.y;
    const int lane  = tid & 63;
    const int wave  = tid >> 6;        // 0..7
    const int r     = tid >> 3;        // 0..63 ; rows h = r + 64*i
    const int c8    = tid & 7;         // float4 group: t_local = c8*4..+3
    const int lr    = lane >> 3;       // DMA: row within 8-row group
    const int lc    = lane & 7;        // DMA: float4 col within 128-B run

    const float L2E = 1.44269504088896340736f;

    // dec values are chunk-invariant: hoist (16 regs, saves per-chunk loads)
    float dh[16];
    #pragma unroll
    for (int i = 0; i < 16; ++i) dh[i] = dec[b*H + r + 64*i];

    float acc[16];
    #pragma unroll
    for (int i = 0; i < 16; ++i) acc[i] = 0.f;

    // ---------- async-stage chunk 0 ----------
    // Each wave: 16 x global_load_lds_dwordx4, each = 8 rows x 128 B from
    // HBM -> 1 KB linear LDS (wave-uniform base + lane*16, matching
    // row-major [h][32] exactly; both sides linear per rule 21).
    {
        const int t0 = split * CHUNKS * TC;
        #pragma unroll
        for (int j = 0; j < 16; ++j) {
            const int row0 = (wave*16 + j) * 8;
            const float* g = enc + (size_t)(row0 + lr)*BT + b*T + t0 + lc*4;
            __builtin_amdgcn_global_load_lds((gp_t)g, (lp_t)&buf[row0*TC], 16, 0, 0);
        }
    }
    BAR_ALL();

    for (int c = 0; c < CHUNKS; ++c) {
        // ---------- LDS -> registers (16 x ds_read_b128) ----------
        float4 v[16];
        #pragma unroll
        for (int i = 0; i < 16; ++i)
            v[i] = *reinterpret_cast<const float4*>(&buf[(r + 64*i)*TC + c8*4]);
        BAR_LGKM();                     // reads COMPLETED -> buf reusable
        __builtin_amdgcn_sched_barrier(0);

        // ---------- async-stage chunk c+1 (overlaps all of P1-P3) ----------
        if (c + 1 < CHUNKS) {           // guard: c+1==CHUNKS would read OOB
            const int t0n = (split*CHUNKS + c + 1) * TC;
            #pragma unroll
            for (int j = 0; j < 16; ++j) {
                const int row0 = (wave*16 + j) * 8;
                const float* g = enc + (size_t)(row0 + lr)*BT + b*T + t0n + lc*4;
                __builtin_amdgcn_global_load_lds((gp_t)g, (lp_t)&buf[row0*TC], 16, 0, 0);
            }
        }

        // ---------- P1: dot + max + min ----------
        float4 s4  = make_float4(0.f, 0.f, 0.f, 0.f);
        float4 mx4 = make_float4(-INFINITY, -INFINITY, -INFINITY, -INFINITY);
        float4 mn4 = make_float4( INFINITY,  INFINITY,  INFINITY,  INFINITY);
        #pragma unroll
        for (int i = 0; i < 16; ++i) {
            s4.x = fmaf(v[i].x, dh[i], s4.x); s4.y = fmaf(v[i].y, dh[i], s4.y);
            s4.z = fmaf(v[i].z, dh[i], s4.z); s4.w = fmaf(v[i].w, dh[i], s4.w);
            mx4.x = fmaxf(mx4.x, v[i].x); mx4.y = fmaxf(mx4.y, v[i].y);
            mx4.z = fmaxf(mx4.z, v[i].z); mx4.w = fmaxf(mx4.w, v[i].w);
            mn4.x = fminf(mn4.x, v[i].x); mn4.y = fminf(mn4.y, v[i].y);
            mn4.z = fminf(mn4.z, v[i].z); mn4.w = fminf(mn4.w, v[i].w);
        }
        #pragma unroll
        for (int off = 8; off <= 32; off <<= 1) {
            s4.x += __shfl_xor(s4.x, off); s4.y += __shfl_xor(s4.y, off);
            s4.z += __shfl_xor(s4.z, off); s4.w += __shfl_xor(s4.w, off);
            mx4.x = fmaxf(mx4.x, __shfl_xor(mx4.x, off)); mx4.y = fmaxf(mx4.y, __shfl_xor(mx4.y, off));
            mx4.z = fmaxf(mx4.z, __shfl_xor(mx4.z, off)); mx4.w = fmaxf(mx4.w, __shfl_xor(mx4.w, off));
            mn4.x = fminf(mn4.x, __shfl_xor(mn4.x, off)); mn4.y = fminf(mn4.y, __shfl_xor(mn4.y, off));
            mn4.z = fminf(mn4.z, __shfl_xor(mn4.z, off)); mn4.w = fminf(mn4.w, __shfl_xor(mn4.w, off));
        }
        if (lane < 8) {
            *reinterpret_cast<float4*>(&rbuf[0][wave][lane*4]) = s4;
            *reinterpret_cast<float4*>(&rbuf[1][wave][lane*4]) = mx4;
            *reinterpret_cast<float4*>(&rbuf[2][wave][lane*4]) = mn4;
        }
        BAR_LGKM();
        if (tid < TC) {
            float s  = rbuf[0][0][tid];
            float mx = rbuf[1][0][tid];
            float mn = rbuf[2][0][tid];
            #pragma unroll
            for (int w = 1; w < 8; ++w) {
                s += rbuf[0][w][tid];
                mx = fmaxf(mx, rbuf[1][w][tid]);
                mn = fminf(mn, rbuf[2][w][tid]);
            }
            const float m = (s >= 0.f) ? s*mx : s*mn;   // true max_h(e*s)
            prm[0][tid] = s * L2E;
            prm[1][tid] = m * L2E;
        }
        BAR_LGKM();

        // ---------- P2: exp in place + denominator ----------
        {
            const float4 sv = *reinterpret_cast<const float4*>(&prm[0][c8*4]);
            const float4 mv = *reinterpret_cast<const float4*>(&prm[1][c8*4]);
            float4 d4 = make_float4(0.f, 0.f, 0.f, 0.f);
            #pragma unroll
            for (int i = 0; i < 16; ++i) {
                v[i].x = ex2(fmaf(v[i].x, sv.x, -mv.x));
                v[i].y = ex2(fmaf(v[i].y, sv.y, -mv.y));
                v[i].z = ex2(fmaf(v[i].z, sv.z, -mv.z));
                v[i].w = ex2(fmaf(v[i].w, sv.w, -mv.w));
                d4.x += v[i].x; d4.y += v[i].y; d4.z += v[i].z; d4.w += v[i].w;
            }
            #pragma unroll
            for (int off = 8; off <= 32; off <<= 1) {
                d4.x += __shfl_xor(d4.x, off); d4.y += __shfl_xor(d4.y, off);
                d4.z += __shfl_xor(d4.z, off); d4.w += __shfl_xor(d4.w, off);
            }
            if (lane < 8)
                *reinterpret_cast<float4*>(&rbuf[0][wave][lane*4]) = d4;
        }
        BAR_LGKM();
        if (tid < TC) {
            float d = rbuf[0][0][tid];
            #pragma unroll
            for (int w = 1; w < 8; ++w) d += rbuf[0][w][tid];
            prm[0][tid] = 1.0f / d;
        }
        BAR_LGKM();

        // ---------- P3: acc += ev * recip ----------
        {
            const float4 rv = *reinterpret_cast<const float4*>(&prm[0][c8*4]);
            #pragma unroll
            for (int i = 0; i < 16; ++i) {
                acc[i] = fmaf(v[i].x, rv.x, acc[i]);
                acc[i] = fmaf(v[i].y, rv.y, acc[i]);
                acc[i] = fmaf(v[i].z, rv.z, acc[i]);
                acc[i] = fmaf(v[i].w, rv.w, acc[i]);
            }
        }
        // Drain next chunk's DMA + protect prm/rbuf before next writes.
        BAR_ALL();
        __builtin_amdgcn_sched_barrier(0);
    }

    // reduce acc over the 8 c8-groups, then write split-partials
    #pragma unroll
    for (int i = 0; i < 16; ++i) {
        acc[i] += __shfl_xor(acc[i], 1);
        acc[i] += __shfl_xor(acc[i], 2);
        acc[i] += __shfl_xor(acc[i], 4);
    }
    const size_t wbase = (size_t)(b * SPLIT + split) * H;
    #pragma unroll
    for (int i = 0; i < 16; ++i) {
        if ((i >> 1) == c8)           // each lane stores 2 of its 16 rows
            ws[wbase + r + 64*i] = acc[i];
    }
}

// Reduce the SPLIT partials per (b,h).
__global__ __launch_bounds__(256) void attn_reduce(const float* __restrict__ ws,
                                                   float* __restrict__ out)
{
    const int idx = blockIdx.x * 256 + threadIdx.x;   // 0 .. B*H-1
    const int b = idx >> 10;
    const int h = idx & 1023;
    float s = 0.f;
    #pragma unroll
    for (int sp = 0; sp < SPLIT; ++sp)
        s += ws[(size_t)(b * SPLIT + sp) * H + h];
    out[idx] = s;
}

extern "C" void kernel_launch(void* const* d_in, const int* in_sizes, int n_in,
                              void* d_out, int out_size, void* d_ws, size_t ws_size,
                              hipStream_t stream)
{
    const float* dec = (const float*)d_in[0];   // [B,H]
    const float* enc = (const float*)d_in[1];   // [H,B,T]
    float* out = (float*)d_out;                 // [B,H]
    float* ws  = (float*)d_ws;                  // uses B*SPLIT*H*4 = 1 MB

    attn_main  <<<dim3(SPLIT, B), NT, 0, stream>>>(dec, enc, ws);
    attn_reduce<<<dim3((B*H)/256), 256, 0, stream>>>(ws, out);
}

// Round 2
// 377.949 us; speedup vs baseline: 1.0162x; 1.0162x over previous
//
#include <hip/hip_runtime.h>
#include <math.h>

#define H  1024
#define B  64
#define T  1024
#define BT (B*T)       // 65536
#define TC 32          // t-columns per chunk (128 B per row)
#define SPLIT 4        // blocks per b -> grid 256 = 1 block/CU
#define CHUNKS 8       // (T/SPLIT)/TC
#define NT 512         // 8 waves
#define HROWS 512      // rows per half-buffer

typedef __attribute__((address_space(1))) unsigned int* gp_t;
typedef __attribute__((address_space(3))) unsigned int* lp_t;

__device__ __forceinline__ float ex2(float x) { return __builtin_amdgcn_exp2f(x); }

// Counted-vmcnt pipeline: per wave, each half-chunk = 8 global_load_lds
// instructions. Steady state keeps 16 in flight; vmcnt(8) proves the OLDEST
// half landed (own-wave), then s_barrier proves it for ALL waves. vmcnt(0)
// appears exactly once (final half). No __syncthreads anywhere: that would
// re-introduce the vmcnt(0)-per-barrier drain that cost R1 its pipeline.
#define WAITV8() asm volatile("s_waitcnt vmcnt(8)" ::: "memory")
#define WAITV0() asm volatile("s_waitcnt vmcnt(0)" ::: "memory")
#define WAITL0() asm volatile("s_waitcnt lgkmcnt(0)" ::: "memory")
#define BAR()    __builtin_amdgcn_s_barrier()

// Stage half hb (rows hb*512..+511) of the 32-t window starting at tcol0
// into buf[bi]. Per wave: 8 instrs x (8 rows x 128 B). LDS dest is linear
// (wave-uniform base + lane*16); the SOURCE is slot-swizzled (lc^lr) so that
// LDS[row][slot s] holds global slot s^(row&7)  (rule 21: swizzle via
// pre-swizzled global address, read with the same XOR).
#define STAGE(bi, hb, tcol0) do {                                            \
    _Pragma("unroll")                                                        \
    for (int j = 0; j < 8; ++j) {                                            \
        const int lrow = wave*64 + j*8;                                      \
        const float* g = enc + (size_t)((hb)*HROWS + lrow + lr)*BT           \
                             + b*T + (tcol0) + 4*(lc ^ lr);                  \
        __builtin_amdgcn_global_load_lds((gp_t)g,                            \
            (lp_t)&buf[bi][lrow*TC], 16, 0, 0);                              \
    }                                                                        \
} while (0)

// One block = (b, split); 1 block/CU (128 KB LDS). Each WAVE owns 4
// t-columns per chunk -> softmax reductions are pure 64-lane shfl trees
// (h = lane + 64*i), no cross-wave barriers, no rbuf/prm round-trips.
// Barriers exist only to gate half-buffer reuse (4/chunk, no drains).
__global__ __launch_bounds__(NT)
void attn_main(const float* __restrict__ dec,
               const float* __restrict__ enc,
               float* __restrict__ ws)
{
    __shared__ float buf[2][HROWS * TC];   // 2 x 64 KB half-buffers

    const int tid   = threadIdx.x;
    const int split = blockIdx.x;
    const int b     = blockIdx.y;
    const int lane  = tid & 63;
    const int wave  = tid >> 6;        // 0..7 : owns t-slot (wave*4..+3)
    const int lr    = lane >> 3;       // DMA: row within 8-row group
    const int lc    = lane & 7;        // DMA: float4 slot within 128-B run

    const float L2E = 1.44269504088896340736f;
    const int   t0  = split * CHUNKS * TC;

    // Read slot for this lane is loop-invariant: s = wave ^ (h&7), and
    // h&7 == lane&7 for h = lane + 64*i.
    const float* rd0 = &buf[0][lane*TC + (wave ^ (lane & 7))*4];
    const float* rd1 = &buf[1][lane*TC + (wave ^ (lane & 7))*4];

    // dec is chunk-invariant: hoist (vmcnt drains with the first wait)
    float dh[16];
    #pragma unroll
    for (int i = 0; i < 16; ++i) dh[i] = dec[b*H + lane + 64*i];

    float acc[16];
    #pragma unroll
    for (int i = 0; i < 16; ++i) acc[i] = 0.f;

    // prologue: both halves of chunk 0 in flight (16 outstanding/wave)
    STAGE(0, 0, t0);
    STAGE(1, 1, t0);

    #pragma unroll 1
    for (int c = 0; c < CHUNKS; ++c) {
        const bool more = (c + 1 < CHUNKS);
        const int  tn   = t0 + (c + 1) * TC;

        // ---- half A: rows 0..511 -> v[0..7] ----
        WAITV8();  BAR();                 // every wave's A(c) landed
        float4 v[16];
        #pragma unroll
        for (int i = 0; i < 8; ++i)
            v[i] = *reinterpret_cast<const float4*>(rd0 + i*64*TC);
        WAITL0();  BAR();                 // all waves done reading bufA
        if (more) STAGE(0, 0, tn);        // refill A immediately

        // ---- half B: rows 512..1023 -> v[8..15] ----
        if (more) { WAITV8(); } else { WAITV0(); }
        BAR();                            // every wave's B(c) landed
        #pragma unroll
        for (int i = 0; i < 8; ++i)
            v[8+i] = *reinterpret_cast<const float4*>(rd1 + i*64*TC);
        WAITL0();  BAR();                 // all waves done reading bufB
        if (more) STAGE(1, 1, tn);        // refill B immediately

        // ---- P1: dot + max + min, full-wave shfl reduce (no barriers) ----
        float4 s4  = make_float4(0.f, 0.f, 0.f, 0.f);
        float4 mx4 = make_float4(-INFINITY, -INFINITY, -INFINITY, -INFINITY);
        float4 mn4 = make_float4( INFINITY,  INFINITY,  INFINITY,  INFINITY);
        #pragma unroll
        for (int i = 0; i < 16; ++i) {
            s4.x = fmaf(v[i].x, dh[i], s4.x); s4.y = fmaf(v[i].y, dh[i], s4.y);
            s4.z = fmaf(v[i].z, dh[i], s4.z); s4.w = fmaf(v[i].w, dh[i], s4.w);
            mx4.x = fmaxf(mx4.x, v[i].x); mx4.y = fmaxf(mx4.y, v[i].y);
            mx4.z = fmaxf(mx4.z, v[i].z); mx4.w = fmaxf(mx4.w, v[i].w);
            mn4.x = fminf(mn4.x, v[i].x); mn4.y = fminf(mn4.y, v[i].y);
            mn4.z = fminf(mn4.z, v[i].z); mn4.w = fminf(mn4.w, v[i].w);
        }
        #pragma unroll
        for (int off = 1; off <= 32; off <<= 1) {
            s4.x += __shfl_xor(s4.x, off); s4.y += __shfl_xor(s4.y, off);
            s4.z += __shfl_xor(s4.z, off); s4.w += __shfl_xor(s4.w, off);
            mx4.x = fmaxf(mx4.x, __shfl_xor(mx4.x, off)); mx4.y = fmaxf(mx4.y, __shfl_xor(mx4.y, off));
            mx4.z = fmaxf(mx4.z, __shfl_xor(mx4.z, off)); mx4.w = fmaxf(mx4.w, __shfl_xor(mx4.w, off));
            mn4.x = fminf(mn4.x, __shfl_xor(mn4.x, off)); mn4.y = fminf(mn4.y, __shfl_xor(mn4.y, off));
            mn4.z = fminf(mn4.z, __shfl_xor(mn4.z, off)); mn4.w = fminf(mn4.w, __shfl_xor(mn4.w, off));
        }
        // every lane now has s/mx/mn for this wave's 4 t-columns
        float4 sl, ml;
        sl.x = s4.x*L2E; ml.x = ((s4.x >= 0.f) ? s4.x*mx4.x : s4.x*mn4.x)*L2E;
        sl.y = s4.y*L2E; ml.y = ((s4.y >= 0.f) ? s4.y*mx4.y : s4.y*mn4.y)*L2E;
        sl.z = s4.z*L2E; ml.z = ((s4.z >= 0.f) ? s4.z*mx4.z : s4.z*mn4.z)*L2E;
        sl.w = s4.w*L2E; ml.w = ((s4.w >= 0.f) ? s4.w*mx4.w : s4.w*mn4.w)*L2E;

        // ---- P2: exp in place + denominator (full-wave reduce) ----
        float4 d4 = make_float4(0.f, 0.f, 0.f, 0.f);
        #pragma unroll
        for (int i = 0; i < 16; ++i) {
            v[i].x = ex2(fmaf(v[i].x, sl.x, -ml.x));
            v[i].y = ex2(fmaf(v[i].y, sl.y, -ml.y));
            v[i].z = ex2(fmaf(v[i].z, sl.z, -ml.z));
            v[i].w = ex2(fmaf(v[i].w, sl.w, -ml.w));
            d4.x += v[i].x; d4.y += v[i].y; d4.z += v[i].z; d4.w += v[i].w;
        }
        #pragma unroll
        for (int off = 1; off <= 32; off <<= 1) {
            d4.x += __shfl_xor(d4.x, off); d4.y += __shfl_xor(d4.y, off);
            d4.z += __shfl_xor(d4.z, off); d4.w += __shfl_xor(d4.w, off);
        }
        const float4 rv = make_float4(1.0f/d4.x, 1.0f/d4.y, 1.0f/d4.z, 1.0f/d4.w);

        // ---- P3: acc += ev * recip ----
        #pragma unroll
        for (int i = 0; i < 16; ++i) {
            acc[i] = fmaf(v[i].x, rv.x, acc[i]);
            acc[i] = fmaf(v[i].y, rv.y, acc[i]);
            acc[i] = fmaf(v[i].z, rv.z, acc[i]);
            acc[i] = fmaf(v[i].w, rv.w, acc[i]);
        }
    }

    // 32 partials per (b,h): [split][wave]. No cross-lane reduce needed
    // (each lane owns distinct h rows). Coalesced 256-B stores per instr.
    const size_t wbase = (size_t)((b * SPLIT + split) * 8 + wave) * H;
    #pragma unroll
    for (int i = 0; i < 16; ++i)
        ws[wbase + lane + 64*i] = acc[i];
}

// Reduce the SPLIT*8 = 32 partials per (b,h). 8 MB read, ~2 us.
__global__ __launch_bounds__(256) void attn_reduce(const float* __restrict__ ws,
                                                   float* __restrict__ out)
{
    const int idx = blockIdx.x * 256 + threadIdx.x;   // 0 .. B*H-1
    const int b = idx >> 10;
    const int h = idx & 1023;
    float s = 0.f;
    #pragma unroll
    for (int p = 0; p < SPLIT*8; ++p)
        s += ws[(size_t)(b * SPLIT*8 + p) * H + h];
    out[idx] = s;
}

extern "C" void kernel_launch(void* const* d_in, const int* in_sizes, int n_in,
                              void* d_out, int out_size, void* d_ws, size_t ws_size,
                              hipStream_t stream)
{
    const float* dec = (const float*)d_in[0];   // [B,H]
    const float* enc = (const float*)d_in[1];   // [H,B,T]
    float* out = (float*)d_out;                 // [B,H]
    float* ws  = (float*)d_ws;                  // uses B*32*H*4 = 8 MB

    attn_main  <<<dim3(SPLIT, B), NT, 0, stream>>>(dec, enc, ws);
    attn_reduce<<<dim3((B*H)/256), 256, 0, stream>>>(ws, out);
}

// Round 3
// 377.191 us; speedup vs baseline: 1.0183x; 1.0020x over previous
//
#include <hip/hip_runtime.h>
#include <math.h>

#define H  1024
#define B  64
#define T  1024
#define BT (B*T)       // 65536
#define TC 32          // t-columns per chunk (128 B per row)
#define SPLIT 4        // blocks per b -> grid 256 = 1 block/CU
#define CHUNKS 8       // (T/SPLIT)/TC
#define NT 512         // 8 waves
#define HROWS 512      // rows per half-buffer

typedef __attribute__((address_space(1))) unsigned int* gp_t;
typedef __attribute__((address_space(3))) unsigned int* lp_t;

__device__ __forceinline__ float ex2(float x) { return __builtin_amdgcn_exp2f(x); }

// Counted-vmcnt pipeline: per wave, each half-chunk = 8 global_load_lds
// instructions. Steady state keeps 16 in flight; vmcnt(8) proves the OLDEST
// half landed (own-wave), then s_barrier proves it for ALL waves. vmcnt(0)
// appears exactly once (final half). No __syncthreads anywhere: that would
// re-introduce the vmcnt(0)-per-barrier drain that cost R1 its pipeline.
#define WAITV8() asm volatile("s_waitcnt vmcnt(8)" ::: "memory")
#define WAITV0() asm volatile("s_waitcnt vmcnt(0)" ::: "memory")
#define WAITL0() asm volatile("s_waitcnt lgkmcnt(0)" ::: "memory")
#define BAR()    __builtin_amdgcn_s_barrier()

// Stage half hb (rows hb*512..+511) of the 32-t window starting at tcol0
// into buf[bi]. Per wave: 8 instrs x (8 rows x 128 B). LDS dest is linear
// (wave-uniform base + lane*16); the SOURCE is slot-swizzled (lc^lr) so that
// LDS[row][slot s] holds global slot s^(row&7)  (rule 21: swizzle via
// pre-swizzled global address, read with the same XOR).
#define STAGE(bi, hb, tcol0) do {                                            \
    _Pragma("unroll")                                                        \
    for (int j = 0; j < 8; ++j) {                                            \
        const int lrow = wave*64 + j*8;                                      \
        const float* g = enc + (size_t)((hb)*HROWS + lrow + lr)*BT           \
                             + b*T + (tcol0) + 4*(lc ^ lr);                  \
        __builtin_amdgcn_global_load_lds((gp_t)g,                            \
            (lp_t)&buf[bi][lrow*TC], 16, 0, 0);                              \
    }                                                                        \
} while (0)

// One block = (b, split); 1 block/CU (128 KB LDS). Each WAVE owns 4
// t-columns per chunk -> softmax reductions are pure 64-lane shfl trees
// (h = lane + 64*i), no cross-wave barriers inside the chunk loop.
// Barriers exist only to gate half-buffer reuse (4/chunk, no drains).
// Epilogue: cross-wave reduce through the (dead) staging LDS so ws
// carries 1 MB of split-partials instead of 8 MB of wave-partials.
__global__ __launch_bounds__(NT)
void attn_main(const float* __restrict__ dec,
               const float* __restrict__ enc,
               float* __restrict__ ws)
{
    __shared__ float buf[2][HROWS * TC];   // 2 x 64 KB half-buffers

    const int tid   = threadIdx.x;
    const int split = blockIdx.x;
    const int b     = blockIdx.y;
    const int lane  = tid & 63;
    const int wave  = tid >> 6;        // 0..7 : owns t-slot (wave*4..+3)
    const int lr    = lane >> 3;       // DMA: row within 8-row group
    const int lc    = lane & 7;        // DMA: float4 slot within 128-B run

    const float L2E = 1.44269504088896340736f;
    const int   t0  = split * CHUNKS * TC;

    // Read slot for this lane is loop-invariant: s = wave ^ (h&7), and
    // h&7 == lane&7 for h = lane + 64*i.
    const float* rd0 = &buf[0][lane*TC + (wave ^ (lane & 7))*4];
    const float* rd1 = &buf[1][lane*TC + (wave ^ (lane & 7))*4];

    // dec is chunk-invariant: hoist
    float dh[16];
    #pragma unroll
    for (int i = 0; i < 16; ++i) dh[i] = dec[b*H + lane + 64*i];

    float acc[16];
    #pragma unroll
    for (int i = 0; i < 16; ++i) acc[i] = 0.f;

    // prologue: both halves of chunk 0 in flight (16 outstanding/wave)
    STAGE(0, 0, t0);
    STAGE(1, 1, t0);

    #pragma unroll 1
    for (int c = 0; c < CHUNKS; ++c) {
        const bool more = (c + 1 < CHUNKS);
        const int  tn   = t0 + (c + 1) * TC;

        // ---- half A: rows 0..511 -> v[0..7] ----
        WAITV8();  BAR();                 // every wave's A(c) landed
        float4 v[16];
        #pragma unroll
        for (int i = 0; i < 8; ++i)
            v[i] = *reinterpret_cast<const float4*>(rd0 + i*64*TC);
        WAITL0();  BAR();                 // all waves done reading bufA
        if (more) STAGE(0, 0, tn);        // refill A immediately

        // ---- half B: rows 512..1023 -> v[8..15] ----
        if (more) { WAITV8(); } else { WAITV0(); }
        BAR();                            // every wave's B(c) landed
        #pragma unroll
        for (int i = 0; i < 8; ++i)
            v[8+i] = *reinterpret_cast<const float4*>(rd1 + i*64*TC);
        WAITL0();  BAR();                 // all waves done reading bufB
        if (more) STAGE(1, 1, tn);        // refill B immediately

        // ---- P1: dot + max + min, full-wave shfl reduce (no barriers) ----
        float4 s4  = make_float4(0.f, 0.f, 0.f, 0.f);
        float4 mx4 = make_float4(-INFINITY, -INFINITY, -INFINITY, -INFINITY);
        float4 mn4 = make_float4( INFINITY,  INFINITY,  INFINITY,  INFINITY);
        #pragma unroll
        for (int i = 0; i < 16; ++i) {
            s4.x = fmaf(v[i].x, dh[i], s4.x); s4.y = fmaf(v[i].y, dh[i], s4.y);
            s4.z = fmaf(v[i].z, dh[i], s4.z); s4.w = fmaf(v[i].w, dh[i], s4.w);
            mx4.x = fmaxf(mx4.x, v[i].x); mx4.y = fmaxf(mx4.y, v[i].y);
            mx4.z = fmaxf(mx4.z, v[i].z); mx4.w = fmaxf(mx4.w, v[i].w);
            mn4.x = fminf(mn4.x, v[i].x); mn4.y = fminf(mn4.y, v[i].y);
            mn4.z = fminf(mn4.z, v[i].z); mn4.w = fminf(mn4.w, v[i].w);
        }
        #pragma unroll
        for (int off = 1; off <= 32; off <<= 1) {
            s4.x += __shfl_xor(s4.x, off); s4.y += __shfl_xor(s4.y, off);
            s4.z += __shfl_xor(s4.z, off); s4.w += __shfl_xor(s4.w, off);
            mx4.x = fmaxf(mx4.x, __shfl_xor(mx4.x, off)); mx4.y = fmaxf(mx4.y, __shfl_xor(mx4.y, off));
            mx4.z = fmaxf(mx4.z, __shfl_xor(mx4.z, off)); mx4.w = fmaxf(mx4.w, __shfl_xor(mx4.w, off));
            mn4.x = fminf(mn4.x, __shfl_xor(mn4.x, off)); mn4.y = fminf(mn4.y, __shfl_xor(mn4.y, off));
            mn4.z = fminf(mn4.z, __shfl_xor(mn4.z, off)); mn4.w = fminf(mn4.w, __shfl_xor(mn4.w, off));
        }
        // every lane now has s/mx/mn for this wave's 4 t-columns
        float4 sl, ml;
        sl.x = s4.x*L2E; ml.x = ((s4.x >= 0.f) ? s4.x*mx4.x : s4.x*mn4.x)*L2E;
        sl.y = s4.y*L2E; ml.y = ((s4.y >= 0.f) ? s4.y*mx4.y : s4.y*mn4.y)*L2E;
        sl.z = s4.z*L2E; ml.z = ((s4.z >= 0.f) ? s4.z*mx4.z : s4.z*mn4.z)*L2E;
        sl.w = s4.w*L2E; ml.w = ((s4.w >= 0.f) ? s4.w*mx4.w : s4.w*mn4.w)*L2E;

        // ---- P2: exp in place + denominator (full-wave reduce) ----
        float4 d4 = make_float4(0.f, 0.f, 0.f, 0.f);
        #pragma unroll
        for (int i = 0; i < 16; ++i) {
            v[i].x = ex2(fmaf(v[i].x, sl.x, -ml.x));
            v[i].y = ex2(fmaf(v[i].y, sl.y, -ml.y));
            v[i].z = ex2(fmaf(v[i].z, sl.z, -ml.z));
            v[i].w = ex2(fmaf(v[i].w, sl.w, -ml.w));
            d4.x += v[i].x; d4.y += v[i].y; d4.z += v[i].z; d4.w += v[i].w;
        }
        #pragma unroll
        for (int off = 1; off <= 32; off <<= 1) {
            d4.x += __shfl_xor(d4.x, off); d4.y += __shfl_xor(d4.y, off);
            d4.z += __shfl_xor(d4.z, off); d4.w += __shfl_xor(d4.w, off);
        }
        const float4 rv = make_float4(1.0f/d4.x, 1.0f/d4.y, 1.0f/d4.z, 1.0f/d4.w);

        // ---- P3: acc += ev * recip ----
        #pragma unroll
        for (int i = 0; i < 16; ++i) {
            acc[i] = fmaf(v[i].x, rv.x, acc[i]);
            acc[i] = fmaf(v[i].y, rv.y, acc[i]);
            acc[i] = fmaf(v[i].z, rv.z, acc[i]);
            acc[i] = fmaf(v[i].w, rv.w, acc[i]);
        }
    }

    // ---- epilogue: cross-wave reduce through the dead staging LDS ----
    // acc[i] holds h = lane + 64*i for this wave's 4 t-columns. Sum the 8
    // wave contributions in-block so ws carries only SPLIT partials (1 MB).
    float* red = &buf[0][0];               // 8 x 1024 floats = 32 KB
    #pragma unroll
    for (int i = 0; i < 16; ++i)
        red[wave*H + lane + 64*i] = acc[i];   // consecutive lanes -> no conflict
    WAITL0();  BAR();

    // each thread reduces 2 h values; float2 reads are 2-way aliased (free)
    {
        const int h0 = tid * 2;
        float2 s = make_float2(0.f, 0.f);
        #pragma unroll
        for (int w = 0; w < 8; ++w) {
            const float2 p = *reinterpret_cast<const float2*>(&red[w*H + h0]);
            s.x += p.x; s.y += p.y;
        }
        *reinterpret_cast<float2*>(&ws[(size_t)(b*SPLIT + split)*H + h0]) = s;
    }
}

// Reduce the SPLIT=4 partials per (b,h). 1 MB read, <1 us.
__global__ __launch_bounds__(256) void attn_reduce(const float* __restrict__ ws,
                                                   float* __restrict__ out)
{
    const int idx = blockIdx.x * 256 + threadIdx.x;   // 0 .. B*H-1
    const int b = idx >> 10;
    const int h = idx & 1023;
    float s = 0.f;
    #pragma unroll
    for (int p = 0; p < SPLIT; ++p)
        s += ws[(size_t)(b*SPLIT + p) * H + h];
    out[idx] = s;
}

extern "C" void kernel_launch(void* const* d_in, const int* in_sizes, int n_in,
                              void* d_out, int out_size, void* d_ws, size_t ws_size,
                              hipStream_t stream)
{
    const float* dec = (const float*)d_in[0];   // [B,H]
    const float* enc = (const float*)d_in[1];   // [H,B,T]
    float* out = (float*)d_out;                 // [B,H]
    float* ws  = (float*)d_ws;                  // uses B*SPLIT*H*4 = 1 MB

    attn_main  <<<dim3(SPLIT, B), NT, 0, stream>>>(dec, enc, ws);
    attn_reduce<<<dim3((B*H)/256), 256, 0, stream>>>(ws, out);
}